// Round 9
// baseline (260.564 us; speedup 1.0000x reference)
//
#include <hip/hip_runtime.h>
#include <stdint.h>

// Problem constants
#define N_BATCH 400000
#define BM 64                  // rows per tile
#define NBLK (N_BATCH / BM)    // 6250 tiles
#define PGRID 1280             // persistent blocks (~5/CU); grid-stride over tiles
// d_ws layout: [0,128KB): hi bf16 weights (4 layers x 16384)
//              [128KB,256KB): lo bf16 weights
//              [256KB,+512B): bo' (folded output bias, f32[128])

typedef __bf16 bf16x8 __attribute__((ext_vector_type(8)));
typedef float  f32x4  __attribute__((ext_vector_type(4)));

__device__ __forceinline__ uint16_t f2bf(float f) {
    union { float f; uint32_t u; } x; x.f = f;
    uint32_t u = x.u;
    uint32_t r = (u + 0x7FFFu + ((u >> 16) & 1u)) >> 16;   // RNE
    return (uint16_t)r;
}
__device__ __forceinline__ float bf2f(uint16_t h) {
    union { uint32_t u; float f; } x; x.u = ((uint32_t)h) << 16;
    return x.f;
}
// swizzled element index: chan ^ ((row&7)<<3)
__device__ __forceinline__ int swzi(int row, int chan) {
    return row * 128 + (chan ^ ((row & 7) << 3));
}

// ---------------- weight pack kernel (hi/lo bf16 split) ----------------
// pw[L][ks][nf][lane][j] = W_L[ks*32 + (lane>>4)*8 + j][nf*16 + (lane&15)]
// L=3 is Wo' = Wo @ blockdiag(B^T x4)
__global__ void pack_kernel(const float* __restrict__ W1, const float* __restrict__ W2,
                            const float* __restrict__ W3, const float* __restrict__ Wo,
                            const float* __restrict__ bo, const float* __restrict__ B,
                            uint16_t* __restrict__ pwh, uint16_t* __restrict__ pwl,
                            float* __restrict__ bo2) {
    if (blockIdx.x == 256) {
        int t = threadIdx.x;
        if (t < 128) {
            int dim = t >> 5, j = t & 31;
            float s = 0.f;
            for (int d = 0; d < 15; ++d) s += bo[dim * 15 + d] * B[j * 15 + d];
            bo2[t] = s;
        }
        return;
    }
    int gid = blockIdx.x * 256 + threadIdx.x;   // 0 .. 65535
    int L    = gid >> 14;
    int r    = gid & 16383;
    int j    = r & 7;
    int lane = (r >> 3) & 63;
    int nf   = (r >> 9) & 7;
    int ks   = r >> 12;
    int k = ks * 32 + (lane >> 4) * 8 + j;
    int n = nf * 16 + (lane & 15);
    float v;
    if (L == 3) {
        int dim = n >> 5, jj = n & 31;
        float s = 0.f;
        for (int d = 0; d < 15; ++d) s += Wo[k * 60 + dim * 15 + d] * B[jj * 15 + d];
        v = s;
    } else {
        const float* W = (L == 0) ? W1 : (L == 1) ? W2 : W3;
        v = W[k * 128 + n];
    }
    uint16_t h = f2bf(v);
    pwh[gid] = h;
    pwl[gid] = f2bf(v - bf2f(h));
}

// ---------------- fused main kernel: persistent + phase-skewed ----------------
__global__ void __launch_bounds__(256) cpab_kernel(
    const float* __restrict__ x, const float* __restrict__ W0,
    const float* __restrict__ b0, const float* __restrict__ b1,
    const float* __restrict__ b2, const float* __restrict__ b3,
    const __bf16* __restrict__ pwh, const __bf16* __restrict__ pwl,
    const float* __restrict__ bo2,
    float* __restrict__ outz, float* __restrict__ outl)
{
    // 32 KB LDS: H hi/lo planes; f32 A overlays both.
    __shared__ __align__(16) uint8_t smem[32 * 1024];
    __bf16* Hh = (__bf16*)smem;                // 16KB
    __bf16* Hl = Hh + BM * 128;                // 16KB
    float*  Af = (float*)smem;                 // overlays Hh+Hl (64x128 f32)

    const int tid  = threadIdx.x;
    const int lane = tid & 63;
    const int wid  = tid >> 6;
    const int ml   = lane & 15;
    const int hl   = lane >> 4;

    // Deliberate start skew: de-phase co-resident blocks so one block's MFMA
    // overlaps others' VALU phases. (b%5) x ~3200 cyc; one-time cost <=5.3us.
    {
        int sk = (blockIdx.x % 5) * 25;
        for (int i = 0; i < sk; ++i) __builtin_amdgcn_s_sleep(2);
    }

    for (int blk = blockIdx.x; blk < NBLK; blk += PGRID) {
        const float* xrow = x + (size_t)blk * (BM * 8);

        // ---- layer 0: H0 = x1 @ W0 + b0  (K=4, f32 VALU) -> Hh/Hl  (R2-exact)
        {
            int j0 = (tid & 15) * 8;
            float wc[4][8], bc[8];
            #pragma unroll
            for (int k = 0; k < 4; ++k) {
                float4 lo = *(const float4*)&W0[k * 128 + j0];
                float4 hi = *(const float4*)&W0[k * 128 + j0 + 4];
                wc[k][0]=lo.x; wc[k][1]=lo.y; wc[k][2]=lo.z; wc[k][3]=lo.w;
                wc[k][4]=hi.x; wc[k][5]=hi.y; wc[k][6]=hi.z; wc[k][7]=hi.w;
            }
            {
                float4 lo = *(const float4*)&b0[j0];
                float4 hi = *(const float4*)&b0[j0 + 4];
                bc[0]=lo.x; bc[1]=lo.y; bc[2]=lo.z; bc[3]=lo.w;
                bc[4]=hi.x; bc[5]=hi.y; bc[6]=hi.z; bc[7]=hi.w;
            }
            #pragma unroll
            for (int i = 0; i < 4; ++i) {
                int row = (tid >> 4) + i * 16;
                float4 xv = *(const float4*)&xrow[row * 8];
                bf16x8 hv, lv;
                #pragma unroll
                for (int jj = 0; jj < 8; ++jj) {
                    float v = bc[jj] + xv.x*wc[0][jj] + xv.y*wc[1][jj] + xv.z*wc[2][jj] + xv.w*wc[3][jj];
                    __bf16 h = (__bf16)v;          // HW RNE cast == f2bf
                    hv[jj] = h;
                    lv[jj] = (__bf16)(v - (float)h);
                }
                int idx = swzi(row, j0);
                *(bf16x8*)&Hh[idx] = hv;
                *(bf16x8*)&Hl[idx] = lv;
            }
        }
        __syncthreads();

        // ---- 64x128x128 MFMA layer, 4-term hi/lo split (R2-exact), IN-PLACE.
        auto gemm = [&](const __bf16* wh, const __bf16* wl,
                        const float* bias, bool relu, bool final_f32) {
            float bv0 = bias[wid * 32 + 0  + ml];
            float bv1 = bias[wid * 32 + 16 + ml];

            f32x4 acc[4][2];
            #pragma unroll
            for (int m = 0; m < 4; ++m)
                #pragma unroll
                for (int n = 0; n < 2; ++n)
                    acc[m][n] = (f32x4){0.f, 0.f, 0.f, 0.f};

            __builtin_amdgcn_s_setprio(1);
            #pragma unroll
            for (int ks = 0; ks < 4; ++ks) {
                bf16x8 ah[4], al[4];
                #pragma unroll
                for (int m = 0; m < 4; ++m) {
                    int idx = swzi(m * 16 + ml, ks * 32 + hl * 8);
                    ah[m] = *(const bf16x8*)&Hh[idx];
                    al[m] = *(const bf16x8*)&Hl[idx];
                }
                #pragma unroll
                for (int n = 0; n < 2; ++n) {
                    int nf = wid * 2 + n;
                    int widx = ((ks * 8 + nf) * 64 + lane) * 8;
                    bf16x8 bh = *(const bf16x8*)&wh[widx];
                    bf16x8 bl = *(const bf16x8*)&wl[widx];
                    #pragma unroll
                    for (int m = 0; m < 4; ++m) {
                        // small terms first (R2 order)
                        acc[m][n] = __builtin_amdgcn_mfma_f32_16x16x32_bf16(al[m], bl, acc[m][n], 0, 0, 0);
                        acc[m][n] = __builtin_amdgcn_mfma_f32_16x16x32_bf16(al[m], bh, acc[m][n], 0, 0, 0);
                        acc[m][n] = __builtin_amdgcn_mfma_f32_16x16x32_bf16(ah[m], bl, acc[m][n], 0, 0, 0);
                        acc[m][n] = __builtin_amdgcn_mfma_f32_16x16x32_bf16(ah[m], bh, acc[m][n], 0, 0, 0);
                    }
                }
            }
            __builtin_amdgcn_s_setprio(0);
            __syncthreads();   // all reads of H complete across the block
            #pragma unroll
            for (int n = 0; n < 2; ++n) {
                int col = wid * 32 + n * 16 + ml;
                float bv = n ? bv1 : bv0;
                #pragma unroll
                for (int m = 0; m < 4; ++m) {
                    #pragma unroll
                    for (int r = 0; r < 4; ++r) {
                        int row = m * 16 + hl * 4 + r;
                        float v = acc[m][n][r] + bv;
                        if (relu) v = fmaxf(v, 0.f);
                        int idx = swzi(row, col);
                        if (final_f32) {
                            Af[idx] = v;
                        } else {
                            __bf16 h = (__bf16)v;   // HW RNE cast == f2bf
                            Hh[idx] = h;
                            Hl[idx] = (__bf16)(v - (float)h);
                        }
                    }
                }
            }
            __syncthreads();
        };

        gemm(pwh + 0*16384, pwl + 0*16384, b1,  true,  false);
        gemm(pwh + 1*16384, pwl + 1*16384, b2,  true,  false);
        gemm(pwh + 2*16384, pwl + 2*16384, b3,  true,  false);
        gemm(pwh + 3*16384, pwl + 3*16384, bo2, false, true);
        // Af[row][swz(dim*32 + 2c {,+1})] = (a,b) per row, dim, cell — f32.

        // ---- CPAB closed-form integration: 1 element per thread (exact ref)
        {
            int row = tid >> 2, dim = tid & 3;
            float xx = xrow[row * 8 + 4 + dim];
            int c = (int)floorf(xx * 16.f);
            c = min(max(c, 0), 15);
            float t = 1.f, logg = 0.f;
            bool done = false;
            #pragma unroll 1
            for (int it = 0; it < 18; ++it) {       // nC + 2 = 18 (ref scan length)
                if (__all(done)) break;
                int ci = swzi(row, (dim << 5) + 2 * c);
                float2 ab = *(const float2*)&Af[ci];
                float a = ab.x, b = ab.y;
                float v = a * xx + b;
                bool small_a = fabsf(a) < 1e-8f;
                float a_safe = small_a ? 1.f : a;
                float eat = expf(a * t);
                float psi = small_a ? (xx + b * t) : (eat * xx + (b / a_safe) * (eat - 1.f));
                float left  = (float)c * 0.0625f;
                float right = (float)(c + 1) * 0.0625f;
                bool inside = (psi >= left) && (psi <= right);
                float xc = (v >= 0.f) ? right : left;
                float v_safe = (fabsf(v) < 1e-8f) ? 1.f : v;
                float b_safe = (fabsf(b) < 1e-8f) ? 1.f : b;
                float ratio = fmaxf((a * xc + b) / v_safe, 1e-8f);
                float thit = small_a ? ((xc - xx) / b_safe) : (logf(ratio) / a_safe);
                float tau = inside ? t : thit;
                bool new_done = done || inside;
                if (!done) {
                    xx = inside ? psi : xc;
                    logg = logg + a * tau;
                }
                if (!new_done) {
                    t = t - thit;
                    c = min(max(c + ((v >= 0.f) ? 1 : -1), 0), 15);
                }
                done = new_done;
            }
            size_t grow = (size_t)blk * BM + row;
            outz[grow * 8 + 4 + dim] = xx;
            outl[grow * 8 + 4 + dim] = logg;
            outz[grow * 8 + dim]     = xrow[row * 8 + dim];   // identity lower half
            outl[grow * 8 + dim]     = 0.f;
        }
        __syncthreads();   // integration reads of Af done before next tile's L0 writes
    }
}

extern "C" void kernel_launch(void* const* d_in, const int* in_sizes, int n_in,
                              void* d_out, int out_size, void* d_ws, size_t ws_size,
                              hipStream_t stream) {
    const float* x  = (const float*)d_in[0];
    const float* W0 = (const float*)d_in[1];
    const float* b0 = (const float*)d_in[2];
    const float* W1 = (const float*)d_in[3];
    const float* b1 = (const float*)d_in[4];
    const float* W2 = (const float*)d_in[5];
    const float* b2 = (const float*)d_in[6];
    const float* W3 = (const float*)d_in[7];
    const float* b3 = (const float*)d_in[8];
    const float* Wo = (const float*)d_in[9];
    const float* bo = (const float*)d_in[10];
    const float* B  = (const float*)d_in[11];

    uint16_t* pwh = (uint16_t*)d_ws;
    uint16_t* pwl = pwh + 4 * 16384;
    float*    bo2 = (float*)(pwl + 4 * 16384);
    float*    outz = (float*)d_out;
    float*    outl = outz + (size_t)N_BATCH * 8;

    hipLaunchKernelGGL(pack_kernel, dim3(257), dim3(256), 0, stream,
                       W1, W2, W3, Wo, bo, B, pwh, pwl, bo2);
    hipLaunchKernelGGL(cpab_kernel, dim3(PGRID), dim3(256), 0, stream,
                       x, W0, b0, b1, b2, b3,
                       (const __bf16*)pwh, (const __bf16*)pwl, bo2, outz, outl);
}

// Round 11
// 186.815 us; speedup vs baseline: 1.3948x; 1.3948x over previous
//
#include <hip/hip_runtime.h>
#include <stdint.h>

// Problem constants
#define N_BATCH 400000
#define BM 32                  // rows per block (16 KB LDS, 2 waves -> 10 blocks/CU)
#define NBLK (N_BATCH / BM)    // 12500
// d_ws layout: [0,128KB): hi bf16 weights (4 layers x 16384)
//              [128KB,256KB): lo bf16 weights
//              [256KB,+512B): bo' (folded output bias, f32[128])

typedef __bf16 bf16x8 __attribute__((ext_vector_type(8)));
typedef float  f32x4  __attribute__((ext_vector_type(4)));

__device__ __forceinline__ uint16_t f2bf(float f) {
    union { float f; uint32_t u; } x; x.f = f;
    uint32_t u = x.u;
    uint32_t r = (u + 0x7FFFu + ((u >> 16) & 1u)) >> 16;   // RNE
    return (uint16_t)r;
}
__device__ __forceinline__ float bf2f(uint16_t h) {
    union { uint32_t u; float f; } x; x.u = ((uint32_t)h) << 16;
    return x.f;
}
// swizzled element index within a 32x128 tile: chan ^ ((row&7)<<3)
__device__ __forceinline__ int swzi(int row, int chan) {
    return row * 128 + (chan ^ ((row & 7) << 3));
}

// ---------------- weight pack kernel (hi/lo bf16 split) ----------------
// pw[L][ks][nf][lane][j] = W_L[ks*32 + (lane>>4)*8 + j][nf*16 + (lane&15)]
// L=3 is Wo' = Wo @ blockdiag(B^T x4)
__global__ void pack_kernel(const float* __restrict__ W1, const float* __restrict__ W2,
                            const float* __restrict__ W3, const float* __restrict__ Wo,
                            const float* __restrict__ bo, const float* __restrict__ B,
                            uint16_t* __restrict__ pwh, uint16_t* __restrict__ pwl,
                            float* __restrict__ bo2) {
    if (blockIdx.x == 256) {
        int t = threadIdx.x;
        if (t < 128) {
            int dim = t >> 5, j = t & 31;
            float s = 0.f;
            for (int d = 0; d < 15; ++d) s += bo[dim * 15 + d] * B[j * 15 + d];
            bo2[t] = s;
        }
        return;
    }
    int gid = blockIdx.x * 256 + threadIdx.x;   // 0 .. 65535
    int L    = gid >> 14;
    int r    = gid & 16383;
    int j    = r & 7;
    int lane = (r >> 3) & 63;
    int nf   = (r >> 9) & 7;
    int ks   = r >> 12;
    int k = ks * 32 + (lane >> 4) * 8 + j;
    int n = nf * 16 + (lane & 15);
    float v;
    if (L == 3) {
        int dim = n >> 5, jj = n & 31;
        float s = 0.f;
        for (int d = 0; d < 15; ++d) s += Wo[k * 60 + dim * 15 + d] * B[jj * 15 + d];
        v = s;
    } else {
        const float* W = (L == 0) ? W1 : (L == 1) ? W2 : W3;
        v = W[k * 128 + n];
    }
    uint16_t h = f2bf(v);
    pwh[gid] = h;
    pwl[gid] = f2bf(v - bf2f(h));
}

// ---------------- fused main kernel: 2-wave blocks, 16 KB LDS ----------------
__global__ void __launch_bounds__(128) cpab_kernel(
    const float* __restrict__ x, const float* __restrict__ W0,
    const float* __restrict__ b0, const float* __restrict__ b1,
    const float* __restrict__ b2, const float* __restrict__ b3,
    const __bf16* __restrict__ pwh, const __bf16* __restrict__ pwl,
    const float* __restrict__ bo2,
    float* __restrict__ outz, float* __restrict__ outl)
{
    // 16 KB LDS: H hi/lo planes (32x128 each); f32 A overlays both.
    __shared__ __align__(16) uint8_t smem[16 * 1024];
    __bf16* Hh = (__bf16*)smem;                // 8 KB
    __bf16* Hl = Hh + BM * 128;                // 8 KB
    float*  Af = (float*)smem;                 // overlays Hh+Hl (32x128 f32)

    const int tid  = threadIdx.x;
    const int blk  = blockIdx.x;
    const int lane = tid & 63;
    const int wid  = tid >> 6;                 // 0..1
    const int ml   = lane & 15;
    const int hl   = lane >> 4;
    const float* xrow = x + (size_t)blk * (BM * 8);

    // ---- layer 0: H0 = x1 @ W0 + b0  (K=4, f32 VALU) -> Hh/Hl  (R5-exact numerics)
    {
        int j0 = (tid & 15) * 8;
        float wc[4][8], bc[8];
        #pragma unroll
        for (int k = 0; k < 4; ++k) {
            float4 lo = *(const float4*)&W0[k * 128 + j0];
            float4 hi = *(const float4*)&W0[k * 128 + j0 + 4];
            wc[k][0]=lo.x; wc[k][1]=lo.y; wc[k][2]=lo.z; wc[k][3]=lo.w;
            wc[k][4]=hi.x; wc[k][5]=hi.y; wc[k][6]=hi.z; wc[k][7]=hi.w;
        }
        {
            float4 lo = *(const float4*)&b0[j0];
            float4 hi = *(const float4*)&b0[j0 + 4];
            bc[0]=lo.x; bc[1]=lo.y; bc[2]=lo.z; bc[3]=lo.w;
            bc[4]=hi.x; bc[5]=hi.y; bc[6]=hi.z; bc[7]=hi.w;
        }
        #pragma unroll
        for (int i = 0; i < 4; ++i) {
            int row = (tid >> 4) + i * 8;          // rows 0..31
            float4 xv = *(const float4*)&xrow[row * 8];
            bf16x8 hv, lv;
            #pragma unroll
            for (int jj = 0; jj < 8; ++jj) {
                float v = bc[jj] + xv.x*wc[0][jj] + xv.y*wc[1][jj] + xv.z*wc[2][jj] + xv.w*wc[3][jj];
                __bf16 h = (__bf16)v;              // HW RNE cast == f2bf
                hv[jj] = h;
                lv[jj] = (__bf16)(v - (float)h);
            }
            int idx = swzi(row, j0);
            *(bf16x8*)&Hh[idx] = hv;
            *(bf16x8*)&Hl[idx] = lv;
        }
    }
    __syncthreads();

    // ---- 32x128x128 MFMA layer, 4-term hi/lo split (R5-exact numerics), IN-PLACE.
    // N-split across 2 waves (4 nf each); every wave reads the full 32x128 tile
    // into registers before the write-back barrier. Race-free. Per-output
    // accumulation sequence identical to R5 -> bit-identical results.
    auto gemm = [&](const __bf16* wh, const __bf16* wl,
                    const float* bias, bool relu, bool final_f32) {
        float bv[4];
        #pragma unroll
        for (int n = 0; n < 4; ++n) bv[n] = bias[wid * 64 + n * 16 + ml];

        f32x4 acc[2][4];
        #pragma unroll
        for (int m = 0; m < 2; ++m)
            #pragma unroll
            for (int n = 0; n < 4; ++n)
                acc[m][n] = (f32x4){0.f, 0.f, 0.f, 0.f};

        __builtin_amdgcn_s_setprio(1);
        #pragma unroll
        for (int ks = 0; ks < 4; ++ks) {
            bf16x8 ah[2], al[2];
            #pragma unroll
            for (int m = 0; m < 2; ++m) {
                int idx = swzi(m * 16 + ml, ks * 32 + hl * 8);
                ah[m] = *(const bf16x8*)&Hh[idx];
                al[m] = *(const bf16x8*)&Hl[idx];
            }
            #pragma unroll
            for (int n = 0; n < 4; ++n) {
                int nf = wid * 4 + n;
                int widx = ((ks * 8 + nf) * 64 + lane) * 8;
                bf16x8 bh = *(const bf16x8*)&wh[widx];
                bf16x8 bl = *(const bf16x8*)&wl[widx];
                #pragma unroll
                for (int m = 0; m < 2; ++m) {
                    // small terms first (R2/R5 order)
                    acc[m][n] = __builtin_amdgcn_mfma_f32_16x16x32_bf16(al[m], bl, acc[m][n], 0, 0, 0);
                    acc[m][n] = __builtin_amdgcn_mfma_f32_16x16x32_bf16(al[m], bh, acc[m][n], 0, 0, 0);
                    acc[m][n] = __builtin_amdgcn_mfma_f32_16x16x32_bf16(ah[m], bl, acc[m][n], 0, 0, 0);
                    acc[m][n] = __builtin_amdgcn_mfma_f32_16x16x32_bf16(ah[m], bh, acc[m][n], 0, 0, 0);
                }
            }
        }
        __builtin_amdgcn_s_setprio(0);
        __syncthreads();   // all reads of H complete across the block
        #pragma unroll
        for (int n = 0; n < 4; ++n) {
            int col = wid * 64 + n * 16 + ml;
            #pragma unroll
            for (int m = 0; m < 2; ++m) {
                #pragma unroll
                for (int r = 0; r < 4; ++r) {
                    int row = m * 16 + hl * 4 + r;
                    float v = acc[m][n][r] + bv[n];
                    if (relu) v = fmaxf(v, 0.f);
                    int idx = swzi(row, col);
                    if (final_f32) {
                        Af[idx] = v;
                    } else {
                        __bf16 h = (__bf16)v;      // HW RNE cast == f2bf
                        Hh[idx] = h;
                        Hl[idx] = (__bf16)(v - (float)h);
                    }
                }
            }
        }
        __syncthreads();
    };

    gemm(pwh + 0*16384, pwl + 0*16384, b1,  true,  false);
    gemm(pwh + 1*16384, pwl + 1*16384, b2,  true,  false);
    gemm(pwh + 2*16384, pwl + 2*16384, b3,  true,  false);
    gemm(pwh + 3*16384, pwl + 3*16384, bo2, false, true);
    // Af[row][swz(dim*32 + 2c {,+1})] = (a,b) per row, dim, cell — f32.

    // ---- CPAB closed-form integration: 1 element per thread (exact ref semantics)
    {
        int row = tid >> 2, dim = tid & 3;        // 128 threads = 32 rows x 4 dims
        float xx = xrow[row * 8 + 4 + dim];
        int c = (int)floorf(xx * 16.f);
        c = min(max(c, 0), 15);
        float t = 1.f, logg = 0.f;
        bool done = false;
        #pragma unroll 1
        for (int it = 0; it < 18; ++it) {       // nC + 2 = 18 (ref scan length)
            if (__all(done)) break;
            int ci = swzi(row, (dim << 5) + 2 * c);
            float2 ab = *(const float2*)&Af[ci];
            float a = ab.x, b = ab.y;
            float v = a * xx + b;
            bool small_a = fabsf(a) < 1e-8f;
            float a_safe = small_a ? 1.f : a;
            float eat = expf(a * t);
            float psi = small_a ? (xx + b * t) : (eat * xx + (b / a_safe) * (eat - 1.f));
            float left  = (float)c * 0.0625f;
            float right = (float)(c + 1) * 0.0625f;
            bool inside = (psi >= left) && (psi <= right);
            float xc = (v >= 0.f) ? right : left;
            float v_safe = (fabsf(v) < 1e-8f) ? 1.f : v;
            float b_safe = (fabsf(b) < 1e-8f) ? 1.f : b;
            float ratio = fmaxf((a * xc + b) / v_safe, 1e-8f);
            float thit = small_a ? ((xc - xx) / b_safe) : (logf(ratio) / a_safe);
            float tau = inside ? t : thit;
            bool new_done = done || inside;
            if (!done) {
                xx = inside ? psi : xc;
                logg = logg + a * tau;
            }
            if (!new_done) {
                t = t - thit;
                c = min(max(c + ((v >= 0.f) ? 1 : -1), 0), 15);
            }
            done = new_done;
        }
        size_t grow = (size_t)blk * BM + row;
        outz[grow * 8 + 4 + dim] = xx;
        outl[grow * 8 + 4 + dim] = logg;
        outz[grow * 8 + dim]     = xrow[row * 8 + dim];   // identity lower half
        outl[grow * 8 + dim]     = 0.f;
    }
}

extern "C" void kernel_launch(void* const* d_in, const int* in_sizes, int n_in,
                              void* d_out, int out_size, void* d_ws, size_t ws_size,
                              hipStream_t stream) {
    const float* x  = (const float*)d_in[0];
    const float* W0 = (const float*)d_in[1];
    const float* b0 = (const float*)d_in[2];
    const float* W1 = (const float*)d_in[3];
    const float* b1 = (const float*)d_in[4];
    const float* W2 = (const float*)d_in[5];
    const float* b2 = (const float*)d_in[6];
    const float* W3 = (const float*)d_in[7];
    const float* b3 = (const float*)d_in[8];
    const float* Wo = (const float*)d_in[9];
    const float* bo = (const float*)d_in[10];
    const float* B  = (const float*)d_in[11];

    uint16_t* pwh = (uint16_t*)d_ws;
    uint16_t* pwl = pwh + 4 * 16384;
    float*    bo2 = (float*)(pwl + 4 * 16384);
    float*    outz = (float*)d_out;
    float*    outl = outz + (size_t)N_BATCH * 8;

    hipLaunchKernelGGL(pack_kernel, dim3(257), dim3(256), 0, stream,
                       W1, W2, W3, Wo, bo, B, pwh, pwl, bo2);
    hipLaunchKernelGGL(cpab_kernel, dim3(NBLK), dim3(128), 0, stream,
                       x, W0, b0, b1, b2, b3,
                       (const __bf16*)pwh, (const __bf16*)pwl, bo2, outz, outl);
}

// Round 12
// 177.819 us; speedup vs baseline: 1.4653x; 1.0506x over previous
//
#include <hip/hip_runtime.h>
#include <stdint.h>

// Problem constants
#define N_BATCH 400000
#define BM 64                 // rows per block
#define NBLK (N_BATCH / BM)   // 6250
// d_ws layout: [0,128KB): hi bf16 weights (4 layers x 16384)
//              [128KB,256KB): lo bf16 weights
//              [256KB,+512B): bo' (folded output bias, f32[128])

typedef __bf16 bf16x8 __attribute__((ext_vector_type(8)));
typedef float  f32x4  __attribute__((ext_vector_type(4)));

__device__ __forceinline__ uint16_t f2bf(float f) {
    union { float f; uint32_t u; } x; x.f = f;
    uint32_t u = x.u;
    uint32_t r = (u + 0x7FFFu + ((u >> 16) & 1u)) >> 16;   // RNE
    return (uint16_t)r;
}
__device__ __forceinline__ float bf2f(uint16_t h) {
    union { uint32_t u; float f; } x; x.u = ((uint32_t)h) << 16;
    return x.f;
}
// swizzled element index: chan ^ ((row&7)<<3)
__device__ __forceinline__ int swzi(int row, int chan) {
    return row * 128 + (chan ^ ((row & 7) << 3));
}

// ---------------- weight pack kernel (hi/lo bf16 split) ----------------
// pw[L][ks][nf][lane][j] = W_L[ks*32 + (lane>>4)*8 + j][nf*16 + (lane&15)]
// L=3 is Wo' = Wo @ blockdiag(B^T x4)
__global__ void pack_kernel(const float* __restrict__ W1, const float* __restrict__ W2,
                            const float* __restrict__ W3, const float* __restrict__ Wo,
                            const float* __restrict__ bo, const float* __restrict__ B,
                            uint16_t* __restrict__ pwh, uint16_t* __restrict__ pwl,
                            float* __restrict__ bo2) {
    if (blockIdx.x == 256) {
        int t = threadIdx.x;
        if (t < 128) {
            int dim = t >> 5, j = t & 31;
            float s = 0.f;
            for (int d = 0; d < 15; ++d) s += bo[dim * 15 + d] * B[j * 15 + d];
            bo2[t] = s;
        }
        return;
    }
    int gid = blockIdx.x * 256 + threadIdx.x;   // 0 .. 65535
    int L    = gid >> 14;
    int r    = gid & 16383;
    int j    = r & 7;
    int lane = (r >> 3) & 63;
    int nf   = (r >> 9) & 7;
    int ks   = r >> 12;
    int k = ks * 32 + (lane >> 4) * 8 + j;
    int n = nf * 16 + (lane & 15);
    float v;
    if (L == 3) {
        int dim = n >> 5, jj = n & 31;
        float s = 0.f;
        for (int d = 0; d < 15; ++d) s += Wo[k * 60 + dim * 15 + d] * B[jj * 15 + d];
        v = s;
    } else {
        const float* W = (L == 0) ? W1 : (L == 1) ? W2 : W3;
        v = W[k * 128 + n];
    }
    uint16_t h = f2bf(v);
    pwh[gid] = h;
    pwl[gid] = f2bf(v - bf2f(h));
}

// ---------------- fused main kernel ----------------
__global__ void __launch_bounds__(256) cpab_kernel(
    const float* __restrict__ x, const float* __restrict__ W0,
    const float* __restrict__ b0, const float* __restrict__ b1,
    const float* __restrict__ b2, const float* __restrict__ b3,
    const __bf16* __restrict__ pwh, const __bf16* __restrict__ pwl,
    const float* __restrict__ bo2,
    float* __restrict__ outz, float* __restrict__ outl)
{
    // Exactly 32 KB LDS: H hi/lo planes; f32 A overlays both.
    __shared__ __align__(16) uint8_t smem[32 * 1024];
    __bf16* Hh = (__bf16*)smem;                // 16KB
    __bf16* Hl = Hh + BM * 128;                // 16KB
    float*  Af = (float*)smem;                 // overlays Hh+Hl (64x128 f32)

    const int tid  = threadIdx.x;
    const int blk  = blockIdx.x;
    const int lane = tid & 63;
    const int wid  = tid >> 6;
    const int ml   = lane & 15;
    const int hl   = lane >> 4;
    const float* xrow = x + (size_t)blk * (BM * 8);

    // ---- layer 0: H0 = x1 @ W0 + b0  (K=4, f32 VALU) -> Hh/Hl  (R5-exact numerics)
    {
        int j0 = (tid & 15) * 8;
        float wc[4][8], bc[8];
        #pragma unroll
        for (int k = 0; k < 4; ++k) {
            float4 lo = *(const float4*)&W0[k * 128 + j0];
            float4 hi = *(const float4*)&W0[k * 128 + j0 + 4];
            wc[k][0]=lo.x; wc[k][1]=lo.y; wc[k][2]=lo.z; wc[k][3]=lo.w;
            wc[k][4]=hi.x; wc[k][5]=hi.y; wc[k][6]=hi.z; wc[k][7]=hi.w;
        }
        {
            float4 lo = *(const float4*)&b0[j0];
            float4 hi = *(const float4*)&b0[j0 + 4];
            bc[0]=lo.x; bc[1]=lo.y; bc[2]=lo.z; bc[3]=lo.w;
            bc[4]=hi.x; bc[5]=hi.y; bc[6]=hi.z; bc[7]=hi.w;
        }
        #pragma unroll
        for (int i = 0; i < 4; ++i) {
            int row = (tid >> 4) + i * 16;
            float4 xv = *(const float4*)&xrow[row * 8];
            bf16x8 hv, lv;
            #pragma unroll
            for (int jj = 0; jj < 8; ++jj) {
                float v = bc[jj] + xv.x*wc[0][jj] + xv.y*wc[1][jj] + xv.z*wc[2][jj] + xv.w*wc[3][jj];
                __bf16 h = (__bf16)v;              // HW RNE cast == f2bf
                hv[jj] = h;
                lv[jj] = (__bf16)(v - (float)h);
            }
            int idx = swzi(row, j0);
            *(bf16x8*)&Hh[idx] = hv;
            *(bf16x8*)&Hl[idx] = lv;
        }
    }
    __syncthreads();

    // ---- 64x128x128 MFMA layer, 4-term hi/lo split, IN-PLACE.
    // Per-accumulator term order (al*bl, al*bh, ah*bl, ah*bh) and ks order are
    // IDENTICAL to R5 -> bit-identical results. Only the instruction
    // interleave changed: term-outer / acc-inner, so consecutive MFMAs hit
    // different accumulators (8 independent chains) and dependency latency
    // is hidden.
    auto gemm = [&](const __bf16* wh, const __bf16* wl,
                    const float* bias, bool relu, bool final_f32) {
        float bv0 = bias[wid * 32 + 0  + ml];
        float bv1 = bias[wid * 32 + 16 + ml];

        f32x4 acc[4][2];
        #pragma unroll
        for (int m = 0; m < 4; ++m)
            #pragma unroll
            for (int n = 0; n < 2; ++n)
                acc[m][n] = (f32x4){0.f, 0.f, 0.f, 0.f};

        __builtin_amdgcn_s_setprio(1);
        #pragma unroll
        for (int ks = 0; ks < 4; ++ks) {
            bf16x8 ah[4], al[4];
            #pragma unroll
            for (int m = 0; m < 4; ++m) {
                int idx = swzi(m * 16 + ml, ks * 32 + hl * 8);
                ah[m] = *(const bf16x8*)&Hh[idx];
                al[m] = *(const bf16x8*)&Hl[idx];
            }
            bf16x8 bh[2], bl[2];
            #pragma unroll
            for (int n = 0; n < 2; ++n) {
                int nf = wid * 2 + n;
                int widx = ((ks * 8 + nf) * 64 + lane) * 8;
                bh[n] = *(const bf16x8*)&wh[widx];
                bl[n] = *(const bf16x8*)&wl[widx];
            }
            // term 0: al*bl  (8 independent MFMAs)
            #pragma unroll
            for (int n = 0; n < 2; ++n)
                #pragma unroll
                for (int m = 0; m < 4; ++m)
                    acc[m][n] = __builtin_amdgcn_mfma_f32_16x16x32_bf16(al[m], bl[n], acc[m][n], 0, 0, 0);
            // term 1: al*bh
            #pragma unroll
            for (int n = 0; n < 2; ++n)
                #pragma unroll
                for (int m = 0; m < 4; ++m)
                    acc[m][n] = __builtin_amdgcn_mfma_f32_16x16x32_bf16(al[m], bh[n], acc[m][n], 0, 0, 0);
            // term 2: ah*bl
            #pragma unroll
            for (int n = 0; n < 2; ++n)
                #pragma unroll
                for (int m = 0; m < 4; ++m)
                    acc[m][n] = __builtin_amdgcn_mfma_f32_16x16x32_bf16(ah[m], bl[n], acc[m][n], 0, 0, 0);
            // term 3: ah*bh
            #pragma unroll
            for (int n = 0; n < 2; ++n)
                #pragma unroll
                for (int m = 0; m < 4; ++m)
                    acc[m][n] = __builtin_amdgcn_mfma_f32_16x16x32_bf16(ah[m], bh[n], acc[m][n], 0, 0, 0);
        }
        __builtin_amdgcn_s_setprio(0);
        __syncthreads();   // all reads of H complete across the block
        #pragma unroll
        for (int n = 0; n < 2; ++n) {
            int col = wid * 32 + n * 16 + ml;
            float bv = n ? bv1 : bv0;
            #pragma unroll
            for (int m = 0; m < 4; ++m) {
                #pragma unroll
                for (int r = 0; r < 4; ++r) {
                    int row = m * 16 + hl * 4 + r;
                    float v = acc[m][n][r] + bv;
                    if (relu) v = fmaxf(v, 0.f);
                    int idx = swzi(row, col);
                    if (final_f32) {
                        Af[idx] = v;
                    } else {
                        __bf16 h = (__bf16)v;      // HW RNE cast == f2bf
                        Hh[idx] = h;
                        Hl[idx] = (__bf16)(v - (float)h);
                    }
                }
            }
        }
        __syncthreads();
    };

    gemm(pwh + 0*16384, pwl + 0*16384, b1,  true,  false);
    gemm(pwh + 1*16384, pwl + 1*16384, b2,  true,  false);
    gemm(pwh + 2*16384, pwl + 2*16384, b3,  true,  false);
    gemm(pwh + 3*16384, pwl + 3*16384, bo2, false, true);
    // Af[row][swz(dim*32 + 2c {,+1})] = (a,b) per row, dim, cell — f32.

    // ---- CPAB closed-form integration: 1 element per thread (exact ref semantics)
    {
        int row = tid >> 2, dim = tid & 3;
        float xx = xrow[row * 8 + 4 + dim];
        int c = (int)floorf(xx * 16.f);
        c = min(max(c, 0), 15);
        float t = 1.f, logg = 0.f;
        bool done = false;
        #pragma unroll 1
        for (int it = 0; it < 18; ++it) {       // nC + 2 = 18 (ref scan length)
            if (__all(done)) break;
            int ci = swzi(row, (dim << 5) + 2 * c);
            float2 ab = *(const float2*)&Af[ci];
            float a = ab.x, b = ab.y;
            float v = a * xx + b;
            bool small_a = fabsf(a) < 1e-8f;
            float a_safe = small_a ? 1.f : a;
            float eat = expf(a * t);
            float psi = small_a ? (xx + b * t) : (eat * xx + (b / a_safe) * (eat - 1.f));
            float left  = (float)c * 0.0625f;
            float right = (float)(c + 1) * 0.0625f;
            bool inside = (psi >= left) && (psi <= right);
            float xc = (v >= 0.f) ? right : left;
            float v_safe = (fabsf(v) < 1e-8f) ? 1.f : v;
            float b_safe = (fabsf(b) < 1e-8f) ? 1.f : b;
            float ratio = fmaxf((a * xc + b) / v_safe, 1e-8f);
            float thit = small_a ? ((xc - xx) / b_safe) : (logf(ratio) / a_safe);
            float tau = inside ? t : thit;
            bool new_done = done || inside;
            if (!done) {
                xx = inside ? psi : xc;
                logg = logg + a * tau;
            }
            if (!new_done) {
                t = t - thit;
                c = min(max(c + ((v >= 0.f) ? 1 : -1), 0), 15);
            }
            done = new_done;
        }
        size_t grow = (size_t)blk * BM + row;
        outz[grow * 8 + 4 + dim] = xx;
        outl[grow * 8 + 4 + dim] = logg;
        outz[grow * 8 + dim]     = xrow[row * 8 + dim];   // identity lower half
        outl[grow * 8 + dim]     = 0.f;
    }
}

extern "C" void kernel_launch(void* const* d_in, const int* in_sizes, int n_in,
                              void* d_out, int out_size, void* d_ws, size_t ws_size,
                              hipStream_t stream) {
    const float* x  = (const float*)d_in[0];
    const float* W0 = (const float*)d_in[1];
    const float* b0 = (const float*)d_in[2];
    const float* W1 = (const float*)d_in[3];
    const float* b1 = (const float*)d_in[4];
    const float* W2 = (const float*)d_in[5];
    const float* b2 = (const float*)d_in[6];
    const float* W3 = (const float*)d_in[7];
    const float* b3 = (const float*)d_in[8];
    const float* Wo = (const float*)d_in[9];
    const float* bo = (const float*)d_in[10];
    const float* B  = (const float*)d_in[11];

    uint16_t* pwh = (uint16_t*)d_ws;
    uint16_t* pwl = pwh + 4 * 16384;
    float*    bo2 = (float*)(pwl + 4 * 16384);
    float*    outz = (float*)d_out;
    float*    outl = outz + (size_t)N_BATCH * 8;

    hipLaunchKernelGGL(pack_kernel, dim3(257), dim3(256), 0, stream,
                       W1, W2, W3, Wo, bo, B, pwh, pwl, bo2);
    hipLaunchKernelGGL(cpab_kernel, dim3(NBLK), dim3(256), 0, stream,
                       x, W0, b0, b1, b2, b3,
                       (const __bf16*)pwh, (const __bf16*)pwl, bo2, outz, outl);
}